// Round 6
// baseline (101.154 us; speedup 1.0000x reference)
//
#include <hip/hip_runtime.h>
#include <hip/hip_bf16.h>
#include <stdint.h>

#define B_   32
#define N_   128
#define E_   8192
#define IMG_ 2048
#define H_   128

typedef __attribute__((ext_vector_type(8))) short bf16x8;
typedef __attribute__((ext_vector_type(4))) float f32x4;

__device__ inline uint16_t f2bf(float x) {
    uint32_t u = __float_as_uint(x);
    uint32_t r = (u + 0x7FFFu + ((u >> 16) & 1u)) >> 16;
    return (uint16_t)r;
}
__device__ inline float bf2f(short x) {
    return __uint_as_float(((uint32_t)(uint16_t)x) << 16);
}

// ---------------------------------------------------------------------------
// Single fused kernel. 256 blocks x 1024 thr, 128 KB LDS -> 1 block/CU,
// all 256 blocks co-resident (deadlock-free producer/consumer flags).
//
//  blocks 224..255: prep (W_img LDS-transpose slice + W_rel slice) -> release
//                   flags[0] (prep_done). Their strips are batches 28-31,
//                   consumed last, so the prep delay is hidden.
//  all blocks:      A-stage (global_load_lds, swizzled source) -> spin
//                   prep_done -> node GEMM + reduce + epilogue + proj strip
//                   (round-3 code) -> release flags[1+batch] (ready).
//  edge phase:      for each batch pair, spin ready (AGENT acquire), gather
//                   2 bf16x8 rows, add, NONTEMPORAL f32x4 stores (134 MB
//                   bypasses L2 -> no write-allocate thrash).
// ---------------------------------------------------------------------------
__global__ __launch_bounds__(1024) void fused_kernel(
    const float* __restrict__ img_feat,
    const float* __restrict__ img_loc,
    const int* __restrict__ edge_src,
    const int* __restrict__ edge_dst,
    const float* __restrict__ W_img,
    const float* __restrict__ b_img,
    const float* __restrict__ W_loc,
    const float* __restrict__ b_loc,
    const float* __restrict__ W_rel,
    const float* __restrict__ b_rel,
    float* __restrict__ out_node,
    float* __restrict__ out_edge,
    uint16_t* __restrict__ Wt_img,
    uint16_t* __restrict__ Wt_rel,
    uint16_t* __restrict__ proj,
    int* flags) {
    __shared__ __align__(16) char lds_raw[131072];
    float (*red)[16][128] = (float (*)[16][128])lds_raw;   // aliases A-tile
    uint16_t (*imgb)[136] = (uint16_t (*)[136])lds_raw;    // aliases too
    float (*tT)[129] = (float (*)[129])lds_raw;            // prep transpose

    int bid = blockIdx.x;
    int tid = threadIdx.x;
    int w  = tid >> 6;       // wave 0..15 = K-slice
    int l  = tid & 63;
    int lr = l & 15;
    int kq = l >> 4;

    // ---- prep phase (blocks 224..255 only; block-uniform branch) ----
    if (bid >= 224) {
        int pb = bid - 224;              // 0..31
        int k0 = pb * 64;
        const float* src = W_img + (size_t)k0 * H_;
        #pragma unroll
        for (int it = 0; it < 8; it++) {
            int idx = it * 1024 + tid;   // [64 k][128 c], coalesced
            tT[idx >> 7][idx & 127] = src[idx];
        }
        __syncthreads();
        {
            int c = tid >> 3, kh = (tid & 7) * 8;
            uint16_t* dst = Wt_img + (size_t)c * IMG_ + k0 + kh;
            #pragma unroll
            for (int j = 0; j < 8; j++) dst[j] = f2bf(tT[kh + j][c]);
        }
        {
            int t2 = pb * 1024 + tid;    // 0..32767
            int c2 = t2 >> 8, k2 = t2 & 255;
            Wt_rel[t2] = f2bf(W_rel[k2 * H_ + c2]);
        }
        __syncthreads();   // drains stores + LDS reuse safety
        if (tid == 0)
            __hip_atomic_fetch_add(&flags[0], 1, __ATOMIC_RELEASE,
                                   __HIP_MEMORY_SCOPE_AGENT);
    }

    // ---- A-stage: 8 x 16B per thread, linear LDS dest, swizzled source ----
    const char* gA = (const char*)(img_feat + (size_t)bid * 16 * IMG_);
    #pragma unroll
    for (int r = 0; r < 8; r++) {
        int L = r * 16384 + tid * 16;
        int row = L >> 13;
        int koff = L & 8191;
        int gsrc = row * 8192 + (koff ^ ((row & 7) << 4));
        __builtin_amdgcn_global_load_lds(
            (const __attribute__((address_space(1))) void*)(gA + gsrc),
            (__attribute__((address_space(3))) void*)(lds_raw + L), 16, 0, 0);
    }

    // ---- wait for ALL prep slices (every block reads full Wt_img) ----
    if (tid == 0) {
        while (__hip_atomic_load(&flags[0], __ATOMIC_RELAXED,
                                 __HIP_MEMORY_SCOPE_AGENT) < 32) {}
        (void)__hip_atomic_load(&flags[0], __ATOMIC_ACQUIRE,
                                __HIP_MEMORY_SCOPE_AGENT);
    }
    __syncthreads();   // joins spin; each wave drained its A-stage loads here

    // ---- node GEMM (K-slice per wave) ----
    int kbase = w * 128 + kq * 8;
    bf16x8 bcur[8];
    #pragma unroll
    for (int n = 0; n < 8; n++)
        bcur[n] = *(const bf16x8*)(Wt_img + (size_t)(n * 16 + lr) * IMG_ + kbase);

    f32x4 acc[8];
    #pragma unroll
    for (int n = 0; n < 8; n++) acc[n] = (f32x4){0.f, 0.f, 0.f, 0.f};
    int sw = (lr & 7) << 4;
    #pragma unroll
    for (int ks = 0; ks < 4; ks++) {
        int koffb = w * 512 + ks * 128 + kq * 32;
        float4 a0 = *(const float4*)(lds_raw + (size_t)lr * 8192 + (koffb ^ sw));
        float4 a1 = *(const float4*)(lds_raw + (size_t)lr * 8192 + ((koffb + 16) ^ sw));
        bf16x8 bn[8];
        if (ks < 3) {
            int kn = kbase + (ks + 1) * 32;
            #pragma unroll
            for (int n = 0; n < 8; n++)
                bn[n] = *(const bf16x8*)(Wt_img + (size_t)(n * 16 + lr) * IMG_ + kn);
        }
        bf16x8 af;
        af[0] = (short)f2bf(a0.x); af[1] = (short)f2bf(a0.y);
        af[2] = (short)f2bf(a0.z); af[3] = (short)f2bf(a0.w);
        af[4] = (short)f2bf(a1.x); af[5] = (short)f2bf(a1.y);
        af[6] = (short)f2bf(a1.z); af[7] = (short)f2bf(a1.w);
        #pragma unroll
        for (int n = 0; n < 8; n++)
            acc[n] = __builtin_amdgcn_mfma_f32_16x16x32_bf16(af, bcur[n], acc[n], 0, 0, 0);
        if (ks < 3) {
            #pragma unroll
            for (int n = 0; n < 8; n++) bcur[n] = bn[n];
        }
    }
    __syncthreads();   // all A-tile reads done before red overwrites it

    // ---- partial dump ----
    #pragma unroll
    for (int n = 0; n < 8; n++)
        #pragma unroll
        for (int r = 0; r < 4; r++)
            red[w][kq * 4 + r][n * 16 + lr] = acc[n][r];
    __syncthreads();

    // ---- reduce + epilogue ----
    int row0 = tid >> 7, col = tid & 127;
    int row1 = row0 + 8;
    float s0 = 0.f, s1 = 0.f;
    #pragma unroll
    for (int ww = 0; ww < 16; ww++) {
        s0 += red[ww][row0][col];
        s1 += red[ww][row1][col];
    }
    __syncthreads();   // red reads done before imgb overwrites

    {
        float bi = b_img[col];
        float bl = b_loc[col];
        float wl[5];
        #pragma unroll
        for (int j = 0; j < 5; j++) wl[j] = W_loc[j * H_ + col];
        float img0 = s0 + bi, img1 = s1 + bi;
        int g0 = bid * 16 + row0, g1 = bid * 16 + row1;
        const float* lc0 = img_loc + g0 * 5;
        const float* lc1 = img_loc + g1 * 5;
        float loc0 = bl, loc1 = bl;
        #pragma unroll
        for (int j = 0; j < 5; j++) { loc0 += lc0[j] * wl[j]; loc1 += lc1[j] * wl[j]; }
        out_node[(size_t)g0 * H_ + col] = img0 + loc0;
        out_node[(size_t)g1 * H_ + col] = img1 + loc1;
        imgb[row0][col] = f2bf(img0);
        imgb[row1][col] = f2bf(img1);
    }
    __syncthreads();   // imgb visible

    // ---- proj GEMM (K=128, 256 cols; wave w -> cols w*16..w*16+15) ----
    {
        int kl = kq * 8;
        int cp = w * 16 + lr;
        const uint16_t* bbase = (cp < 128)
            ? (Wt_rel + (size_t)cp * 256)
            : (Wt_rel + (size_t)(cp - 128) * 256 + 128);
        f32x4 pacc = (f32x4){0.f, 0.f, 0.f, 0.f};
        #pragma unroll
        for (int ks = 0; ks < 4; ks++) {
            int k = ks * 32 + kl;
            bf16x8 af = *(const bf16x8*)(&imgb[lr][k]);
            bf16x8 bf = *(const bf16x8*)(bbase + k);
            pacc = __builtin_amdgcn_mfma_f32_16x16x32_bf16(af, bf, pacc, 0, 0, 0);
        }
        float brel = (cp < 128) ? b_rel[cp] : 0.f;
        #pragma unroll
        for (int r = 0; r < 4; r++) {
            int grow = bid * 16 + kq * 4 + r;
            proj[(size_t)grow * 256 + cp] = f2bf(pacc[r] + brel);
        }
    }
    __syncthreads();   // drains proj stores (vmcnt0 at barrier)
    if (tid == 0)
        __hip_atomic_fetch_add(&flags[1 + (bid >> 3)], 1, __ATOMIC_RELEASE,
                               __HIP_MEMORY_SCOPE_AGENT);

    // ---- edge phase: block streams its 1/256 of each batch pair ----
    int halfsel = tid >> 9;                    // 0: even batch, 1: odd batch
    int o = (bid << 9) | (tid & 511);          // octet in batch, 0..131071
    int e = o >> 4, c = (o & 15) << 3;
    int s = edge_src[e], d = edge_dst[e];
    const uint16_t* ps = proj + (size_t)s * 256 + c;
    const uint16_t* pd = proj + (size_t)d * 256 + 128 + c;
    float* op = out_edge + (size_t)e * H_ + c;

    for (int ib = 0; ib < 16; ib++) {
        if (tid == 0) {
            while (__hip_atomic_load(&flags[1 + 2 * ib], __ATOMIC_RELAXED,
                                     __HIP_MEMORY_SCOPE_AGENT) < 8 ||
                   __hip_atomic_load(&flags[2 + 2 * ib], __ATOMIC_RELAXED,
                                     __HIP_MEMORY_SCOPE_AGENT) < 8) {}
            (void)__hip_atomic_load(&flags[1 + 2 * ib], __ATOMIC_ACQUIRE,
                                    __HIP_MEMORY_SCOPE_AGENT);
        }
        __syncthreads();
        int b = 2 * ib + halfsel;
        bf16x8 a  = *(const bf16x8*)(ps + (size_t)b * (N_ * 256));
        bf16x8 bb = *(const bf16x8*)(pd + (size_t)b * (N_ * 256));
        f32x4 o0, o1;
        o0[0] = bf2f(a[0]) + bf2f(bb[0]);
        o0[1] = bf2f(a[1]) + bf2f(bb[1]);
        o0[2] = bf2f(a[2]) + bf2f(bb[2]);
        o0[3] = bf2f(a[3]) + bf2f(bb[3]);
        o1[0] = bf2f(a[4]) + bf2f(bb[4]);
        o1[1] = bf2f(a[5]) + bf2f(bb[5]);
        o1[2] = bf2f(a[6]) + bf2f(bb[6]);
        o1[3] = bf2f(a[7]) + bf2f(bb[7]);
        float* dst = op + (size_t)b * (E_ * H_);
        __builtin_nontemporal_store(o0, (f32x4*)dst);
        __builtin_nontemporal_store(o1, (f32x4*)(dst + 4));
    }
}

// ---------------------------------------------------------------------------
extern "C" void kernel_launch(void* const* d_in, const int* in_sizes, int n_in,
                              void* d_out, int out_size, void* d_ws, size_t ws_size,
                              hipStream_t stream) {
    const float* img_feat = (const float*)d_in[0];
    const float* img_loc  = (const float*)d_in[1];
    const int*   edge_src = (const int*)d_in[2];
    const int*   edge_dst = (const int*)d_in[3];
    const float* W_img    = (const float*)d_in[4];
    const float* b_img    = (const float*)d_in[5];
    const float* W_loc    = (const float*)d_in[6];
    const float* b_loc    = (const float*)d_in[7];
    const float* W_rel    = (const float*)d_in[8];
    const float* b_rel    = (const float*)d_in[9];

    float* out_node = (float*)d_out;                       // [B,N,H]
    float* out_edge = out_node + (size_t)B_ * N_ * H_;     // [B,E,H]

    // ws: Wt_img 512K | Wt_rel 64K | proj 2M | flags
    char* ws = (char*)d_ws;
    uint16_t* Wt_img = (uint16_t*)ws;
    uint16_t* Wt_rel = (uint16_t*)(ws + 524288);
    uint16_t* proj   = (uint16_t*)(ws + 589824);
    int*      flags  = (int*)(ws + 589824 + 2097152);      // 33 ints

    (void)hipMemsetAsync(flags, 0, 256, stream);

    fused_kernel<<<dim3(256), dim3(1024), 0, stream>>>(
        img_feat, img_loc, edge_src, edge_dst,
        W_img, b_img, W_loc, b_loc, W_rel, b_rel,
        out_node, out_edge, Wt_img, Wt_rel, proj, flags);
}

// Round 7
// 93.893 us; speedup vs baseline: 1.0773x; 1.0773x over previous
//
#include <hip/hip_runtime.h>
#include <hip/hip_bf16.h>
#include <stdint.h>

#define B_   32
#define N_   128
#define E_   8192
#define IMG_ 2048
#define H_   128

typedef __attribute__((ext_vector_type(8))) short bf16x8;
typedef __attribute__((ext_vector_type(4))) float f32x4;

__device__ inline uint16_t f2bf(float x) {
    uint32_t u = __float_as_uint(x);
    uint32_t r = (u + 0x7FFFu + ((u >> 16) & 1u)) >> 16;
    return (uint16_t)r;
}
__device__ inline float bf2f(short x) {
    return __uint_as_float(((uint32_t)(uint16_t)x) << 16);
}

// ---------------------------------------------------------------------------
// P: weight transpose+convert to bf16 k-major.
// blocks 0..31: W_img via LDS transpose (coalesced read AND write).
// blocks 32..159: W_rel strided (tiny, L2-resident).
// ---------------------------------------------------------------------------
__global__ __launch_bounds__(256) void prep_kernel(
    const float* __restrict__ W_img, const float* __restrict__ W_rel,
    uint16_t* __restrict__ Wt_img, uint16_t* __restrict__ Wt_rel) {
    int bid = blockIdx.x, tid = threadIdx.x;
    if (bid < 32) {
        __shared__ float t[64][129];
        int k0 = bid * 64;
        const float* src = W_img + (size_t)k0 * H_;
        #pragma unroll
        for (int it = 0; it < 32; it++) {
            int idx = it * 256 + tid;            // 0..8191 over [64k][128c]
            t[idx >> 7][idx & 127] = src[idx];
        }
        __syncthreads();
        int c = tid >> 1, kh = (tid & 1) * 32;
        uint16_t* dst = Wt_img + (size_t)c * IMG_ + k0 + kh;
        #pragma unroll
        for (int j = 0; j < 32; j++) dst[j] = f2bf(t[kh + j][c]);
    } else {
        int t2 = (bid - 32) * 256 + tid;         // 0..32767
        int c = t2 >> 8, k = t2 & 255;
        Wt_rel[t2] = f2bf(W_rel[k * H_ + c]);
    }
}

// ---------------------------------------------------------------------------
// NODE+PROJ fused (round-3 code — at its HBM floor).
// ---------------------------------------------------------------------------
__global__ __launch_bounds__(1024) void node_proj_kernel(
    const float* __restrict__ img_feat,
    const uint16_t* __restrict__ Wt_img,
    const uint16_t* __restrict__ Wt_rel,
    const float* __restrict__ img_loc,
    const float* __restrict__ b_img,
    const float* __restrict__ W_loc,
    const float* __restrict__ b_loc,
    const float* __restrict__ b_rel,
    float* __restrict__ out_node,
    uint16_t* __restrict__ proj) {
    __shared__ __align__(16) char lds_raw[131072];
    float (*red)[16][128] = (float (*)[16][128])lds_raw;     // aliases A-tile
    uint16_t (*imgb)[136] = (uint16_t (*)[136])lds_raw;      // aliases too

    int strip = blockIdx.x;
    int tid = threadIdx.x;
    int w  = tid >> 6;       // wave 0..15 = K-slice
    int l  = tid & 63;
    int lr = l & 15;
    int kq = l >> 4;

    // ---- stage A: 8 x 16B per thread, linear LDS dest, swizzled source ----
    const char* gA = (const char*)(img_feat + (size_t)strip * 16 * IMG_);
    #pragma unroll
    for (int r = 0; r < 8; r++) {
        int L = r * 16384 + tid * 16;            // linear LDS byte
        int row = L >> 13;                       // 8 KB per fp32 row
        int koff = L & 8191;
        int gsrc = row * 8192 + (koff ^ ((row & 7) << 4));
        __builtin_amdgcn_global_load_lds(
            (const __attribute__((address_space(1))) void*)(gA + gsrc),
            (__attribute__((address_space(3))) void*)(lds_raw + L), 16, 0, 0);
    }

    // ---- prefetch B for ks=0 ----
    int kbase = w * 128 + kq * 8;
    bf16x8 bcur[8];
    #pragma unroll
    for (int n = 0; n < 8; n++)
        bcur[n] = *(const bf16x8*)(Wt_img + (size_t)(n * 16 + lr) * IMG_ + kbase);

    __syncthreads();   // drains vmcnt: A-tile in LDS, bcur in regs

    // ---- phase 1: K-slice GEMM from LDS ----
    f32x4 acc[8];
    #pragma unroll
    for (int n = 0; n < 8; n++) acc[n] = (f32x4){0.f, 0.f, 0.f, 0.f};
    int sw = (lr & 7) << 4;
    #pragma unroll
    for (int ks = 0; ks < 4; ks++) {
        int koffb = w * 512 + ks * 128 + kq * 32;   // byte offset within row
        float4 a0 = *(const float4*)(lds_raw + (size_t)lr * 8192 + (koffb ^ sw));
        float4 a1 = *(const float4*)(lds_raw + (size_t)lr * 8192 + ((koffb + 16) ^ sw));
        bf16x8 bn[8];
        if (ks < 3) {
            int kn = kbase + (ks + 1) * 32;
            #pragma unroll
            for (int n = 0; n < 8; n++)
                bn[n] = *(const bf16x8*)(Wt_img + (size_t)(n * 16 + lr) * IMG_ + kn);
        }
        bf16x8 af;
        af[0] = (short)f2bf(a0.x); af[1] = (short)f2bf(a0.y);
        af[2] = (short)f2bf(a0.z); af[3] = (short)f2bf(a0.w);
        af[4] = (short)f2bf(a1.x); af[5] = (short)f2bf(a1.y);
        af[6] = (short)f2bf(a1.z); af[7] = (short)f2bf(a1.w);
        #pragma unroll
        for (int n = 0; n < 8; n++)
            acc[n] = __builtin_amdgcn_mfma_f32_16x16x32_bf16(af, bcur[n], acc[n], 0, 0, 0);
        if (ks < 3) {
            #pragma unroll
            for (int n = 0; n < 8; n++) bcur[n] = bn[n];
        }
    }
    __syncthreads();   // all A-tile reads done before red overwrites it

    // ---- phase 2: dump partials ----
    #pragma unroll
    for (int n = 0; n < 8; n++)
        #pragma unroll
        for (int r = 0; r < 4; r++)
            red[w][kq * 4 + r][n * 16 + lr] = acc[n][r];
    __syncthreads();

    // ---- phase 3: reduce + epilogue ----
    int row0 = tid >> 7, col = tid & 127;    // rows 0..7
    int row1 = row0 + 8;                     // rows 8..15
    float s0 = 0.f, s1 = 0.f;
    #pragma unroll
    for (int ww = 0; ww < 16; ww++) {
        s0 += red[ww][row0][col];
        s1 += red[ww][row1][col];
    }
    __syncthreads();   // red reads done before imgb overwrites

    {
        float bi = b_img[col];
        float bl = b_loc[col];
        float wl[5];
        #pragma unroll
        for (int j = 0; j < 5; j++) wl[j] = W_loc[j * H_ + col];
        float img0 = s0 + bi, img1 = s1 + bi;
        int g0 = strip * 16 + row0, g1 = strip * 16 + row1;
        const float* lc0 = img_loc + g0 * 5;
        const float* lc1 = img_loc + g1 * 5;
        float loc0 = bl, loc1 = bl;
        #pragma unroll
        for (int j = 0; j < 5; j++) { loc0 += lc0[j] * wl[j]; loc1 += lc1[j] * wl[j]; }
        out_node[(size_t)g0 * H_ + col] = img0 + loc0;
        out_node[(size_t)g1 * H_ + col] = img1 + loc1;
        imgb[row0][col] = f2bf(img0);
        imgb[row1][col] = f2bf(img1);
    }
    __syncthreads();   // imgb visible

    // ---- phase 4: proj GEMM ----
    int kl = kq * 8;
    int cp = w * 16 + lr;
    const uint16_t* bbase = (cp < 128)
        ? (Wt_rel + (size_t)cp * 256)
        : (Wt_rel + (size_t)(cp - 128) * 256 + 128);
    f32x4 pacc = (f32x4){0.f, 0.f, 0.f, 0.f};
    #pragma unroll
    for (int ks = 0; ks < 4; ks++) {
        int k = ks * 32 + kl;
        bf16x8 af = *(const bf16x8*)(&imgb[lr][k]);
        bf16x8 bf = *(const bf16x8*)(bbase + k);
        pacc = __builtin_amdgcn_mfma_f32_16x16x32_bf16(af, bf, pacc, 0, 0, 0);
    }
    float brel = (cp < 128) ? b_rel[cp] : 0.f;
    #pragma unroll
    for (int r = 0; r < 4; r++) {
        int grow = strip * 16 + kq * 4 + r;
        proj[(size_t)grow * 256 + cp] = f2bf(pacc[r] + brel);
    }
}

// ---------------------------------------------------------------------------
// EDGE stream (round-4 ILP structure) + NONTEMPORAL stores: the 134 MB fp32
// write stream bypasses L2 allocation, so the 2 MB proj gather table stays
// L2-resident and the gather->add->store chain hits L2 instead of L3.
// ---------------------------------------------------------------------------
__global__ __launch_bounds__(256) void edge_kernel(
    const uint16_t* __restrict__ proj,
    const int* __restrict__ edge_src,
    const int* __restrict__ edge_dst,
    float* __restrict__ out_edge) {
    int t = blockIdx.x * 256 + threadIdx.x;   // 0..524287
    int b0 = t >> 17;                         // 0..3
    int r  = t & 131071;
    int e  = r >> 4;
    int c  = (r & 15) * 8;
    int s  = edge_src[e];
    int d  = edge_dst[e];
    const uint16_t* ps = proj + ((size_t)(b0 * N_ + s) * 256 + c);
    const uint16_t* pd = proj + ((size_t)(b0 * N_ + d) * 256 + 128 + c);
    float* op = out_edge + ((size_t)(b0 * E_ + e) * H_ + c);
    const size_t PSTR = (size_t)4 * N_ * 256;      // proj elems per 4 batches
    const size_t OSTR = (size_t)4 * E_ * H_;       // out floats per 4 batches

    #pragma unroll
    for (int h = 0; h < 2; h++) {
        bf16x8 av[4], bv[4];
        #pragma unroll
        for (int i = 0; i < 4; i++) {
            size_t it = (size_t)(h * 4 + i);
            av[i] = *(const bf16x8*)(ps + it * PSTR);
            bv[i] = *(const bf16x8*)(pd + it * PSTR);
        }
        #pragma unroll
        for (int i = 0; i < 4; i++) {
            size_t it = (size_t)(h * 4 + i);
            f32x4 o0, o1;
            o0[0] = bf2f(av[i][0]) + bf2f(bv[i][0]);
            o0[1] = bf2f(av[i][1]) + bf2f(bv[i][1]);
            o0[2] = bf2f(av[i][2]) + bf2f(bv[i][2]);
            o0[3] = bf2f(av[i][3]) + bf2f(bv[i][3]);
            o1[0] = bf2f(av[i][4]) + bf2f(bv[i][4]);
            o1[1] = bf2f(av[i][5]) + bf2f(bv[i][5]);
            o1[2] = bf2f(av[i][6]) + bf2f(bv[i][6]);
            o1[3] = bf2f(av[i][7]) + bf2f(bv[i][7]);
            float* dst = op + it * OSTR;
            __builtin_nontemporal_store(o0, (f32x4*)dst);
            __builtin_nontemporal_store(o1, (f32x4*)(dst + 4));
        }
    }
}

// ---------------------------------------------------------------------------
extern "C" void kernel_launch(void* const* d_in, const int* in_sizes, int n_in,
                              void* d_out, int out_size, void* d_ws, size_t ws_size,
                              hipStream_t stream) {
    const float* img_feat = (const float*)d_in[0];
    const float* img_loc  = (const float*)d_in[1];
    const int*   edge_src = (const int*)d_in[2];
    const int*   edge_dst = (const int*)d_in[3];
    const float* W_img    = (const float*)d_in[4];
    const float* b_img    = (const float*)d_in[5];
    const float* W_loc    = (const float*)d_in[6];
    const float* b_loc    = (const float*)d_in[7];
    const float* W_rel    = (const float*)d_in[8];
    const float* b_rel    = (const float*)d_in[9];

    float* out_node = (float*)d_out;                       // [B,N,H]
    float* out_edge = out_node + (size_t)B_ * N_ * H_;     // [B,E,H]

    char* ws = (char*)d_ws;
    uint16_t* Wt_img = (uint16_t*)ws;                      // 512 KB
    uint16_t* Wt_rel = (uint16_t*)(ws + 524288);           // 64 KB
    uint16_t* proj   = (uint16_t*)(ws + 524288 + 65536);   // 2 MB [4096][256]

    prep_kernel<<<dim3(160), dim3(256), 0, stream>>>(W_img, W_rel, Wt_img, Wt_rel);

    node_proj_kernel<<<dim3(256), dim3(1024), 0, stream>>>(
        img_feat, Wt_img, Wt_rel, img_loc, b_img, W_loc, b_loc, b_rel,
        out_node, proj);

    edge_kernel<<<dim3(2048), dim3(256), 0, stream>>>(
        proj, edge_src, edge_dst, out_edge);
}

// Round 8
// 60.044 us; speedup vs baseline: 1.6847x; 1.5637x over previous
//
#include <hip/hip_runtime.h>
#include <hip/hip_bf16.h>
#include <stdint.h>

#define B_   32
#define N_   128
#define E_   8192
#define IMG_ 2048
#define H_   128

typedef __attribute__((ext_vector_type(8))) short bf16x8;
typedef __attribute__((ext_vector_type(4))) float f32x4;

__device__ inline uint16_t f2bf(float x) {
    uint32_t u = __float_as_uint(x);
    uint32_t r = (u + 0x7FFFu + ((u >> 16) & 1u)) >> 16;
    return (uint16_t)r;
}
__device__ inline float bf2f(short x) {
    return __uint_as_float(((uint32_t)(uint16_t)x) << 16);
}

// ---------------------------------------------------------------------------
// P: weight transpose+convert to bf16 k-major (unchanged from round 4).
// ---------------------------------------------------------------------------
__global__ __launch_bounds__(256) void prep_kernel(
    const float* __restrict__ W_img, const float* __restrict__ W_rel,
    uint16_t* __restrict__ Wt_img, uint16_t* __restrict__ Wt_rel) {
    int bid = blockIdx.x, tid = threadIdx.x;
    if (bid < 32) {
        __shared__ float t[64][129];
        int k0 = bid * 64;
        const float* src = W_img + (size_t)k0 * H_;
        #pragma unroll
        for (int it = 0; it < 32; it++) {
            int idx = it * 256 + tid;            // 0..8191 over [64k][128c]
            t[idx >> 7][idx & 127] = src[idx];
        }
        __syncthreads();
        int c = tid >> 1, kh = (tid & 1) * 32;
        uint16_t* dst = Wt_img + (size_t)c * IMG_ + k0 + kh;
        #pragma unroll
        for (int j = 0; j < 32; j++) dst[j] = f2bf(t[kh + j][c]);
    } else {
        int t2 = (bid - 32) * 256 + tid;         // 0..32767
        int c = t2 >> 8, k = t2 & 255;
        Wt_rel[t2] = f2bf(W_rel[k * H_ + c]);
    }
}

// ---------------------------------------------------------------------------
// NODE+PROJ fused (unchanged from round 4 — at its HBM floor).
// ---------------------------------------------------------------------------
__global__ __launch_bounds__(1024) void node_proj_kernel(
    const float* __restrict__ img_feat,
    const uint16_t* __restrict__ Wt_img,
    const uint16_t* __restrict__ Wt_rel,
    const float* __restrict__ img_loc,
    const float* __restrict__ b_img,
    const float* __restrict__ W_loc,
    const float* __restrict__ b_loc,
    const float* __restrict__ b_rel,
    float* __restrict__ out_node,
    uint16_t* __restrict__ proj) {
    __shared__ __align__(16) char lds_raw[131072];
    float (*red)[16][128] = (float (*)[16][128])lds_raw;     // aliases A-tile
    uint16_t (*imgb)[136] = (uint16_t (*)[136])lds_raw;      // aliases too

    int strip = blockIdx.x;
    int tid = threadIdx.x;
    int w  = tid >> 6;       // wave 0..15 = K-slice
    int l  = tid & 63;
    int lr = l & 15;
    int kq = l >> 4;

    // ---- stage A: 8 x 16B per thread, linear LDS dest, swizzled source ----
    const char* gA = (const char*)(img_feat + (size_t)strip * 16 * IMG_);
    #pragma unroll
    for (int r = 0; r < 8; r++) {
        int L = r * 16384 + tid * 16;            // linear LDS byte
        int row = L >> 13;                       // 8 KB per fp32 row
        int koff = L & 8191;
        int gsrc = row * 8192 + (koff ^ ((row & 7) << 4));
        __builtin_amdgcn_global_load_lds(
            (const __attribute__((address_space(1))) void*)(gA + gsrc),
            (__attribute__((address_space(3))) void*)(lds_raw + L), 16, 0, 0);
    }

    // ---- prefetch B for ks=0 ----
    int kbase = w * 128 + kq * 8;
    bf16x8 bcur[8];
    #pragma unroll
    for (int n = 0; n < 8; n++)
        bcur[n] = *(const bf16x8*)(Wt_img + (size_t)(n * 16 + lr) * IMG_ + kbase);

    __syncthreads();   // drains vmcnt: A-tile in LDS, bcur in regs

    // ---- phase 1: K-slice GEMM from LDS ----
    f32x4 acc[8];
    #pragma unroll
    for (int n = 0; n < 8; n++) acc[n] = (f32x4){0.f, 0.f, 0.f, 0.f};
    int sw = (lr & 7) << 4;
    #pragma unroll
    for (int ks = 0; ks < 4; ks++) {
        int koffb = w * 512 + ks * 128 + kq * 32;   // byte offset within row
        float4 a0 = *(const float4*)(lds_raw + (size_t)lr * 8192 + (koffb ^ sw));
        float4 a1 = *(const float4*)(lds_raw + (size_t)lr * 8192 + ((koffb + 16) ^ sw));
        bf16x8 bn[8];
        if (ks < 3) {
            int kn = kbase + (ks + 1) * 32;
            #pragma unroll
            for (int n = 0; n < 8; n++)
                bn[n] = *(const bf16x8*)(Wt_img + (size_t)(n * 16 + lr) * IMG_ + kn);
        }
        bf16x8 af;
        af[0] = (short)f2bf(a0.x); af[1] = (short)f2bf(a0.y);
        af[2] = (short)f2bf(a0.z); af[3] = (short)f2bf(a0.w);
        af[4] = (short)f2bf(a1.x); af[5] = (short)f2bf(a1.y);
        af[6] = (short)f2bf(a1.z); af[7] = (short)f2bf(a1.w);
        #pragma unroll
        for (int n = 0; n < 8; n++)
            acc[n] = __builtin_amdgcn_mfma_f32_16x16x32_bf16(af, bcur[n], acc[n], 0, 0, 0);
        if (ks < 3) {
            #pragma unroll
            for (int n = 0; n < 8; n++) bcur[n] = bn[n];
        }
    }
    __syncthreads();   // all A-tile reads done before red overwrites it

    // ---- phase 2: dump partials ----
    #pragma unroll
    for (int n = 0; n < 8; n++)
        #pragma unroll
        for (int r = 0; r < 4; r++)
            red[w][kq * 4 + r][n * 16 + lr] = acc[n][r];
    __syncthreads();

    // ---- phase 3: reduce + epilogue ----
    int row0 = tid >> 7, col = tid & 127;    // rows 0..7
    int row1 = row0 + 8;                     // rows 8..15
    float s0 = 0.f, s1 = 0.f;
    #pragma unroll
    for (int ww = 0; ww < 16; ww++) {
        s0 += red[ww][row0][col];
        s1 += red[ww][row1][col];
    }
    __syncthreads();   // red reads done before imgb overwrites

    {
        float bi = b_img[col];
        float bl = b_loc[col];
        float wl[5];
        #pragma unroll
        for (int j = 0; j < 5; j++) wl[j] = W_loc[j * H_ + col];
        float img0 = s0 + bi, img1 = s1 + bi;
        int g0 = strip * 16 + row0, g1 = strip * 16 + row1;
        const float* lc0 = img_loc + g0 * 5;
        const float* lc1 = img_loc + g1 * 5;
        float loc0 = bl, loc1 = bl;
        #pragma unroll
        for (int j = 0; j < 5; j++) { loc0 += lc0[j] * wl[j]; loc1 += lc1[j] * wl[j]; }
        out_node[(size_t)g0 * H_ + col] = img0 + loc0;
        out_node[(size_t)g1 * H_ + col] = img1 + loc1;
        imgb[row0][col] = f2bf(img0);
        imgb[row1][col] = f2bf(img1);
    }
    __syncthreads();   // imgb visible

    // ---- phase 4: proj GEMM ----
    int kl = kq * 8;
    int cp = w * 16 + lr;
    const uint16_t* bbase = (cp < 128)
        ? (Wt_rel + (size_t)cp * 256)
        : (Wt_rel + (size_t)(cp - 128) * 256 + 128);
    f32x4 pacc = (f32x4){0.f, 0.f, 0.f, 0.f};
    #pragma unroll
    for (int ks = 0; ks < 4; ks++) {
        int k = ks * 32 + kl;
        bf16x8 af = *(const bf16x8*)(&imgb[lr][k]);
        bf16x8 bf = *(const bf16x8*)(bbase + k);
        pacc = __builtin_amdgcn_mfma_f32_16x16x32_bf16(af, bf, pacc, 0, 0, 0);
    }
    float brel = (cp < 128) ? b_rel[cp] : 0.f;
    #pragma unroll
    for (int r = 0; r < 4; r++) {
        int grow = strip * 16 + kq * 4 + r;
        proj[(size_t)grow * 256 + cp] = f2bf(pacc[r] + brel);
    }
}

// ---------------------------------------------------------------------------
// EDGE stream, LDS-gather version. 512 blocks x 512 thr; block = (batch b,
// 512-edge slice). The batch's whole proj slice (128 rows x 512 B = 64 KB)
// is staged to LDS once (global_load_lds, linear), edge indices (4 KB) too.
// Hot loop: 2x ds_read_b128 -> bf16 add -> 2x coalesced float4 stores.
// No global-read dependency in the hot path; writes are plain cached stores
// (NT proven -35 us in round 7). LDS 70 KB -> 2 blocks/CU, all CUs covered.
// ---------------------------------------------------------------------------
__global__ __launch_bounds__(512) void edge_kernel(
    const uint16_t* __restrict__ proj,
    const int* __restrict__ edge_src,
    const int* __restrict__ edge_dst,
    float* __restrict__ out_edge) {
    __shared__ __align__(16) char plds[65536];   // proj[b]: 128 rows x 512 B
    __shared__ int sidx[512];
    __shared__ int didx[512];

    int bid = blockIdx.x;        // 0..511
    int b   = bid >> 4;          // batch
    int sub = bid & 15;          // 512-edge slice
    int tid = threadIdx.x;

    // stage proj slice (64 KB): 8 x 16 B per thread, linear
    const char* gsrc = (const char*)(proj + (size_t)b * N_ * 256);
    #pragma unroll
    for (int r = 0; r < 8; r++) {
        int L = r * 8192 + tid * 16;
        __builtin_amdgcn_global_load_lds(
            (const __attribute__((address_space(1))) void*)(gsrc + L),
            (__attribute__((address_space(3))) void*)(plds + L), 16, 0, 0);
    }
    int e0 = sub * 512;
    sidx[tid] = edge_src[e0 + tid];
    didx[tid] = edge_dst[e0 + tid];
    __syncthreads();   // drains global_load_lds + idx writes

    float* ob = out_edge + ((size_t)b * E_ + e0) * H_;
    #pragma unroll 4
    for (int it = 0; it < 16; it++) {
        int i  = it * 512 + tid;         // octet id, 0..8191 (512 edges x 16)
        int el = i >> 4;                 // edge within slice
        int c2 = (i & 15) << 4;          // byte offset within half-row
        int s = sidx[el], d = didx[el];
        bf16x8 a  = *(const bf16x8*)(plds + s * 512 + c2);
        bf16x8 bb = *(const bf16x8*)(plds + d * 512 + 256 + c2);
        float4 o0, o1;
        o0.x = bf2f(a[0]) + bf2f(bb[0]);
        o0.y = bf2f(a[1]) + bf2f(bb[1]);
        o0.z = bf2f(a[2]) + bf2f(bb[2]);
        o0.w = bf2f(a[3]) + bf2f(bb[3]);
        o1.x = bf2f(a[4]) + bf2f(bb[4]);
        o1.y = bf2f(a[5]) + bf2f(bb[5]);
        o1.z = bf2f(a[6]) + bf2f(bb[6]);
        o1.w = bf2f(a[7]) + bf2f(bb[7]);
        float* dst = ob + (size_t)i * 8;
        *(float4*)dst = o0;
        *(float4*)(dst + 4) = o1;
    }
}

// ---------------------------------------------------------------------------
extern "C" void kernel_launch(void* const* d_in, const int* in_sizes, int n_in,
                              void* d_out, int out_size, void* d_ws, size_t ws_size,
                              hipStream_t stream) {
    const float* img_feat = (const float*)d_in[0];
    const float* img_loc  = (const float*)d_in[1];
    const int*   edge_src = (const int*)d_in[2];
    const int*   edge_dst = (const int*)d_in[3];
    const float* W_img    = (const float*)d_in[4];
    const float* b_img    = (const float*)d_in[5];
    const float* W_loc    = (const float*)d_in[6];
    const float* b_loc    = (const float*)d_in[7];
    const float* W_rel    = (const float*)d_in[8];
    const float* b_rel    = (const float*)d_in[9];

    float* out_node = (float*)d_out;                       // [B,N,H]
    float* out_edge = out_node + (size_t)B_ * N_ * H_;     // [B,E,H]

    char* ws = (char*)d_ws;
    uint16_t* Wt_img = (uint16_t*)ws;                      // 512 KB
    uint16_t* Wt_rel = (uint16_t*)(ws + 524288);           // 64 KB
    uint16_t* proj   = (uint16_t*)(ws + 524288 + 65536);   // 2 MB [4096][256]

    prep_kernel<<<dim3(160), dim3(256), 0, stream>>>(W_img, W_rel, Wt_img, Wt_rel);

    node_proj_kernel<<<dim3(256), dim3(1024), 0, stream>>>(
        img_feat, Wt_img, Wt_rel, img_loc, b_img, W_loc, b_loc, b_rel,
        out_node, proj);

    edge_kernel<<<dim3(512), dim3(512), 0, stream>>>(
        proj, edge_src, edge_dst, out_edge);
}